// Round 1
// 415.541 us; speedup vs baseline: 1.0103x; 1.0103x over previous
//
#include <hip/hip_runtime.h>
#include <stdint.h>

typedef _Float16 f16;
typedef _Float16 f16x4 __attribute__((ext_vector_type(4)));
typedef _Float16 f16x8 __attribute__((ext_vector_type(8)));
typedef float f32x4 __attribute__((ext_vector_type(4)));

#define NB 8
#define NN 4096
#define CC 768
#define SCALE_F 0.10206207261596577f  // 96^-0.5

// async global->LDS, 16B per lane; LDS dest = wave-uniform base + lane*16
#define GLDS16(gp, lp)                                                       \
  __builtin_amdgcn_global_load_lds(                                          \
      (__attribute__((address_space(1))) void*)(gp),                         \
      (__attribute__((address_space(3))) void*)(lp), 16, 0, 0)

// ---------------------------------------------------------------------------
// Kernel A: fp32 -> fp16 convert + transpose.
//   x1t[b][c][n] = x1[b][n][c]; x2t[b][d][n] = x2[b][n][d]; x2b = f16(x2)
// ---------------------------------------------------------------------------
__global__ __launch_bounds__(256) void k_convert(
    const float* __restrict__ x1, const float* __restrict__ x2,
    f16* __restrict__ x1t, f16* __restrict__ x2t, f16* __restrict__ x2b) {
  __shared__ float tile[64][65];
  const int which = blockIdx.z >> 3;  // 0: x1, 1: x2
  const int b = blockIdx.z & 7;
  const int n0 = blockIdx.x << 6;
  const int c0 = blockIdx.y << 6;
  const float* src = (which ? x2 : x1) + (size_t)b * NN * CC;
  f16* dt = (which ? x2t : x1t) + (size_t)b * CC * NN;
  const int t = threadIdx.x;
  const int rowi = t >> 4;          // 0..15
  const int col4 = (t & 15) << 2;   // 0,4,..,60
#pragma unroll
  for (int it = 0; it < 4; ++it) {
    const int r = it * 16 + rowi;
    const float4 v =
        *reinterpret_cast<const float4*>(&src[(size_t)(n0 + r) * CC + c0 + col4]);
    tile[r][col4 + 0] = v.x;
    tile[r][col4 + 1] = v.y;
    tile[r][col4 + 2] = v.z;
    tile[r][col4 + 3] = v.w;
    if (which) {
      f16x4 o = {(f16)v.x, (f16)v.y, (f16)v.z, (f16)v.w};
      *reinterpret_cast<f16x4*>(
          &x2b[(size_t)b * NN * CC + (size_t)(n0 + r) * CC + c0 + col4]) = o;
    }
  }
  __syncthreads();
  const int c = t >> 2;             // 0..63 (output row within tile)
  const int nb = (t & 3) << 4;      // 0,16,32,48
  f16x8 lo, hi;
#pragma unroll
  for (int j = 0; j < 8; ++j) lo[j] = (f16)tile[nb + j][c];
#pragma unroll
  for (int j = 0; j < 8; ++j) hi[j] = (f16)tile[nb + 8 + j][c];
  f16* o = &dt[(size_t)(c0 + c) * NN + n0 + nb];
  *reinterpret_cast<f16x8*>(o) = lo;
  *reinterpret_cast<f16x8*>(o + 8) = hi;
}

// ---------------------------------------------------------------------------
// Kernel B/D: bt-GEMM: C[m][n] (+)= sum_k A[m][k]*B[n][k]
// 128x128 tile, BK=32, 4 waves each 64x64 (4x4 of 16x16x32 MFMA).
//
// 3-buffer pipeline, 2 tiles in flight (counted vmcnt, never drained to 0 in
// steady state):
//   prologue: stage tiles 0,1 into bufs 0,1
//   iter t:   s_waitcnt vmcnt(4)   (own tile-t loads done; t+1 stays in flight)
//             s_barrier            (all waves' tile-t loads done;
//                                   all waves' tile t-1 ds_reads retired)
//             sched_barrier(0)     (no ds_read / GLDS crosses the barrier)
//             stage tile t+2 into buf (t+2)%3   (= buf of t-1, now free)
//             ds_read buf t%3, 16x MFMA
// Each load gets ~2 iteration periods to complete instead of <1 — hides the
// L2/L3-miss latency that held MfmaUtil at 13%.
//
// LDS XOR-swizzle (both-sides involution, rule #21): LDS dest stays linear
// for global_load_lds; the global SOURCE 16B-chunk is permuted
// c ^= ((row>>1)&3), and the ds_read applies the same XOR. Kills the 8-way
// bank conflict of row-stride-64B ds_read_b128 (4.7M conflicts -> ~0).
//
// 1-D grid + XCD-locality swizzle (assumes hw xcd = blockIdx.x % 8):
//  SWZ=1 (GEMM1): 6x6 tiles, 8 batches, ksplit=4; batch = xcd.
//  SWZ=2 (GEMM2): 32x6 tiles, 8 batches; batch = xcd.
// ---------------------------------------------------------------------------
template <bool ATOMIC, int SWZ>
__global__ __launch_bounds__(256) void k_gemm_bt(
    const f16* __restrict__ A, const f16* __restrict__ B,
    float* __restrict__ C, int klen, int lda, int ldb, int ldc,
    size_t sA, size_t sB, size_t sC) {
  __shared__ __align__(16) f16 As[3][128 * 32];
  __shared__ __align__(16) f16 Bs[3][128 * 32];

  const int lin = blockIdx.x;
  const int xcd = lin & 7;
  const int slot = lin >> 3;
  int bx, by, b, ks;
  if (SWZ == 1) {
    b = xcd;                 // one batch per XCD
    ks = slot / 36;          // 4 sequential K-split phases
    const int item = slot % 36;
    bx = item % 6;
    by = item / 6;
  } else {
    b = xcd;                 // one batch per XCD
    ks = 0;
    bx = slot / 6;           // B n-chunk index (streamed)
    by = slot % 6;           // 6 consecutive tiles share the B chunk
  }

  const f16* Ap = A + (size_t)b * sA + (size_t)by * 128 * lda + (size_t)ks * klen;
  const f16* Bp = B + (size_t)b * sB + (size_t)bx * 128 * ldb + (size_t)ks * klen;
  float* Cp = C + (size_t)b * sC + (size_t)by * 128 * ldc + bx * 128;

  const int tid = threadIdx.x;
  const int wave = tid >> 6;
  const int lane = tid & 63;
  const int wr = wave >> 1;  // wave row (0/1) -> 64-row half
  const int wc = wave & 1;   // wave col (0/1) -> 64-col half

  // staging: wave w loads A rows [32w,32w+32) and B rows [32w,32w+32).
  // LDS row r holds its 4 16B-chunks permuted by XOR s(r)=((r>>1)&3);
  // achieved by permuting the GLOBAL source chunk while LDS dest stays linear.
  const int srow = wave * 32 + (lane >> 2);            // LDS row this lane fills
  const int scg = ((lane & 3) ^ ((srow >> 1) & 3)) * 8;  // swizzled src chunk (f16)
  const f16* ga0 = Ap + (size_t)srow * lda + scg;
  const f16* ga1 = ga0 + (size_t)16 * lda;             // row+16: same XOR term
  const f16* gb0 = Bp + (size_t)srow * ldb + scg;
  const f16* gb1 = gb0 + (size_t)16 * ldb;
  const int lofs0 = wave * 32 * 32;       // wave-uniform LDS offsets
  const int lofs1 = lofs0 + 16 * 32;

  // fragment read offsets: lane holds row (lane&15), k = (lane>>4)*8 .. +7.
  // Apply the same XOR on the 16B chunk; invariant under row+16 so one offset
  // serves all 4 fragment rows.
  const int arow = wr * 64 + (lane & 15);
  const int brow = wc * 64 + (lane & 15);
  const int kc8 = (lane >> 4) * 8;
  const int raofs = arow * 32 + (kc8 ^ (((arow >> 1) & 3) * 8));
  const int rbofs = brow * 32 + (kc8 ^ (((brow >> 1) & 3) * 8));

  f32x4 acc[4][4] = {};

  const int nit = klen >> 5;
  // prologue: stage tile 0 -> buf 0, tile 1 -> buf 1
  GLDS16(ga0, &As[0][lofs0]);
  GLDS16(ga1, &As[0][lofs1]);
  GLDS16(gb0, &Bs[0][lofs0]);
  GLDS16(gb1, &Bs[0][lofs1]);
  ga0 += 32; ga1 += 32; gb0 += 32; gb1 += 32;
  GLDS16(ga0, &As[1][lofs0]);
  GLDS16(ga1, &As[1][lofs1]);
  GLDS16(gb0, &Bs[1][lofs0]);
  GLDS16(gb1, &Bs[1][lofs1]);

  int rb = 0;   // read buffer  (tile it)
  int wb = 2;   // write buffer (tile it+2)
  for (int it = 0; it < nit; ++it) {
    // drain own tile-it loads; keep tile it+1 in flight (never vmcnt(0) in
    // steady state). Last iteration has only 4 outstanding -> must use 0.
    if (it + 1 < nit)
      asm volatile("s_waitcnt vmcnt(4)" ::: "memory");
    else
      asm volatile("s_waitcnt vmcnt(0)" ::: "memory");
    __builtin_amdgcn_s_barrier();
    __builtin_amdgcn_sched_barrier(0);  // nothing crosses the barrier

    if (it + 2 < nit) {
      ga0 += 32; ga1 += 32; gb0 += 32; gb1 += 32;
      GLDS16(ga0, &As[wb][lofs0]);
      GLDS16(ga1, &As[wb][lofs1]);
      GLDS16(gb0, &Bs[wb][lofs0]);
      GLDS16(gb1, &Bs[wb][lofs1]);
    }

    const f16* ra = &As[rb][raofs];
    const f16* rbp = &Bs[rb][rbofs];
    f16x8 af[4], bfv[4];
#pragma unroll
    for (int i = 0; i < 4; ++i)
      af[i] = *reinterpret_cast<const f16x8*>(ra + i * 16 * 32);
#pragma unroll
    for (int j = 0; j < 4; ++j)
      bfv[j] = *reinterpret_cast<const f16x8*>(rbp + j * 16 * 32);
#pragma unroll
    for (int i = 0; i < 4; ++i)
#pragma unroll
      for (int j = 0; j < 4; ++j)
        acc[i][j] = __builtin_amdgcn_mfma_f32_16x16x32_f16(af[i], bfv[j],
                                                           acc[i][j], 0, 0, 0);
    rb = (rb == 2) ? 0 : rb + 1;
    wb = (wb == 2) ? 0 : wb + 1;
  }

  // C/D layout (verified m89/m91, dtype-independent): col=lane&15, row=(lane>>4)*4+reg
  const int col = lane & 15;
  const int rq = (lane >> 4) * 4;
#pragma unroll
  for (int i = 0; i < 4; ++i) {
    const int r0 = wr * 64 + i * 16 + rq;
#pragma unroll
    for (int j = 0; j < 4; ++j) {
      const int cidx = wc * 64 + j * 16 + col;
#pragma unroll
      for (int r = 0; r < 4; ++r) {
        const float v = acc[i][j][r];
        if (ATOMIC)
          atomicAdd(&Cp[(size_t)(r0 + r) * ldc + cidx], v);
        else
          Cp[(size_t)(r0 + r) * ldc + cidx] = v;
      }
    }
  }
}

// ---------------------------------------------------------------------------
// Kernel C: row softmax over 768 logits (SCALE applied here), fp32 -> fp16.
// ---------------------------------------------------------------------------
__global__ __launch_bounds__(256) void k_softmax(const float* __restrict__ S,
                                                 f16* __restrict__ P) {
  const int row = blockIdx.x * 4 + (threadIdx.x >> 6);
  const int lane = threadIdx.x & 63;
  const float* s = S + (size_t)row * CC;
  float v[12];
#pragma unroll
  for (int j = 0; j < 3; ++j) {
    const float4 t = *reinterpret_cast<const float4*>(&s[j * 256 + lane * 4]);
    v[j * 4 + 0] = t.x * SCALE_F;
    v[j * 4 + 1] = t.y * SCALE_F;
    v[j * 4 + 2] = t.z * SCALE_F;
    v[j * 4 + 3] = t.w * SCALE_F;
  }
  float m = v[0];
#pragma unroll
  for (int j = 1; j < 12; ++j) m = fmaxf(m, v[j]);
#pragma unroll
  for (int off = 32; off >= 1; off >>= 1) m = fmaxf(m, __shfl_xor(m, off, 64));
  float sum = 0.f;
#pragma unroll
  for (int j = 0; j < 12; ++j) {
    v[j] = __expf(v[j] - m);
    sum += v[j];
  }
#pragma unroll
  for (int off = 32; off >= 1; off >>= 1) sum += __shfl_xor(sum, off, 64);
  const float inv = 1.0f / sum;
  f16* p = P + (size_t)row * CC;
#pragma unroll
  for (int j = 0; j < 3; ++j) {
    f16x4 o = {(f16)(v[j * 4 + 0] * inv), (f16)(v[j * 4 + 1] * inv),
               (f16)(v[j * 4 + 2] * inv), (f16)(v[j * 4 + 3] * inv)};
    *reinterpret_cast<f16x4*>(&p[j * 256 + lane * 4]) = o;
  }
}

// ---------------------------------------------------------------------------
extern "C" void kernel_launch(void* const* d_in, const int* in_sizes, int n_in,
                              void* d_out, int out_size, void* d_ws,
                              size_t ws_size, hipStream_t stream) {
  const float* x1 = (const float*)d_in[0];
  const float* x2 = (const float*)d_in[1];
  float* out = (float*)d_out;

  const size_t elems = (size_t)NB * NN * CC;  // 25165824
  // x1t/x2t live in d_out (2 * f16 arrays == out fp32 bytes exactly);
  // GEMM2 overwrites out only after GEMM1 consumed them.
  f16* x1t = (f16*)d_out;
  f16* x2t = x1t + elems;
  char* ws = (char*)d_ws;
  f16* x2b = (f16*)ws;                                     // 50.3 MB
  float* S = (float*)(ws + elems * 2);                     // 18.9 MB
  f16* P = (f16*)(ws + elems * 2 + (size_t)NB * CC * CC * 4);  // 9.4 MB
  const size_t need =
      elems * 2 + (size_t)NB * CC * CC * 4 + (size_t)NB * CC * CC * 2;
  if (ws_size < need) return;  // cannot run without scratch

  // A) convert + transpose
  k_convert<<<dim3(NN / 64, CC / 64, 2 * NB), 256, 0, stream>>>(x1, x2, x1t,
                                                                x2t, x2b);
  // B) S = x1t . x2t^T  (split-K x4, atomic accumulate; S pre-zeroed)
  hipMemsetAsync(S, 0, (size_t)NB * CC * CC * 4, stream);
  k_gemm_bt<true, 1><<<dim3(6 * 6 * NB * 4), 256, 0, stream>>>(
      x1t, x2t, S, NN / 4, NN, NN, CC, (size_t)CC * NN, (size_t)CC * NN,
      (size_t)CC * CC);
  // C) P = softmax(SCALE * S) as fp16
  k_softmax<<<dim3(NB * CC / 4), 256, 0, stream>>>(S, P);
  // D) out = P . x2b^T
  k_gemm_bt<false, 2><<<dim3(32 * 6 * NB), 256, 0, stream>>>(
      P, x2b, out, CC, CC, CC, NN, (size_t)CC * CC, (size_t)NN * CC,
      (size_t)CC * NN);
}

// Round 2
// 412.225 us; speedup vs baseline: 1.0184x; 1.0080x over previous
//
#include <hip/hip_runtime.h>
#include <stdint.h>

typedef _Float16 f16;
typedef _Float16 f16x4 __attribute__((ext_vector_type(4)));
typedef _Float16 f16x8 __attribute__((ext_vector_type(8)));
typedef float f32x4 __attribute__((ext_vector_type(4)));

#define NB 8
#define NN 4096
#define CC 768
#define SCALE_F 0.10206207261596577f  // 96^-0.5

// async global->LDS, 16B per lane; LDS dest = wave-uniform base + lane*16
#define GLDS16(gp, lp)                                                       \
  __builtin_amdgcn_global_load_lds(                                          \
      (__attribute__((address_space(1))) void*)(gp),                         \
      (__attribute__((address_space(3))) void*)(lp), 16, 0, 0)

// ---------------------------------------------------------------------------
// Kernel A: fp32 -> fp16 convert + transpose.
//   x1t[b][c][n] = x1[b][n][c]; x2t[b][d][n] = x2[b][n][d]; x2b = f16(x2)
// ---------------------------------------------------------------------------
__global__ __launch_bounds__(256) void k_convert(
    const float* __restrict__ x1, const float* __restrict__ x2,
    f16* __restrict__ x1t, f16* __restrict__ x2t, f16* __restrict__ x2b) {
  __shared__ float tile[64][65];
  const int which = blockIdx.z >> 3;  // 0: x1, 1: x2
  const int b = blockIdx.z & 7;
  const int n0 = blockIdx.x << 6;
  const int c0 = blockIdx.y << 6;
  const float* src = (which ? x2 : x1) + (size_t)b * NN * CC;
  f16* dt = (which ? x2t : x1t) + (size_t)b * CC * NN;
  const int t = threadIdx.x;
  const int rowi = t >> 4;          // 0..15
  const int col4 = (t & 15) << 2;   // 0,4,..,60
#pragma unroll
  for (int it = 0; it < 4; ++it) {
    const int r = it * 16 + rowi;
    const float4 v =
        *reinterpret_cast<const float4*>(&src[(size_t)(n0 + r) * CC + c0 + col4]);
    tile[r][col4 + 0] = v.x;
    tile[r][col4 + 1] = v.y;
    tile[r][col4 + 2] = v.z;
    tile[r][col4 + 3] = v.w;
    if (which) {
      f16x4 o = {(f16)v.x, (f16)v.y, (f16)v.z, (f16)v.w};
      *reinterpret_cast<f16x4*>(
          &x2b[(size_t)b * NN * CC + (size_t)(n0 + r) * CC + c0 + col4]) = o;
    }
  }
  __syncthreads();
  const int c = t >> 2;             // 0..63 (output row within tile)
  const int nb = (t & 3) << 4;      // 0,16,32,48
  f16x8 lo, hi;
#pragma unroll
  for (int j = 0; j < 8; ++j) lo[j] = (f16)tile[nb + j][c];
#pragma unroll
  for (int j = 0; j < 8; ++j) hi[j] = (f16)tile[nb + 8 + j][c];
  f16* o = &dt[(size_t)(c0 + c) * NN + n0 + nb];
  *reinterpret_cast<f16x8*>(o) = lo;
  *reinterpret_cast<f16x8*>(o + 8) = hi;
}

// ---------------------------------------------------------------------------
// Kernel B/D: bt-GEMM: C[m][n] (+)= sum_k A[m][k]*B[n][k]
//
// 256x256 block tile, BK=64, 8 waves (2M x 4N), per-wave tile 128x64
// (HK geometry: FLOP per LDS-read byte = 42.7 vs 32 for 64x64 waves —
// round-1 counters showed the 64x64 structure is LDS-read-bandwidth bound
// at MfmaUtil 14.7%, matching the m134 ds_read_b128 ~12cyc/CU model).
//
// 2-buffer LDS (128 KiB, 1 block/CU, 2 waves/SIMD), 2 tiles in flight:
//   prologue: STAGE(t0->buf0); STAGE(t1->buf1)             [16 outstanding]
//   iter t:   vmcnt(8)  — own tile-t loads done, t+1 stays in flight
//             barrier   — all waves' tile-t loads landed in LDS
//             ds_read sub0 (12xb128) ; 32 MFMA ; ds_read sub1 (12xb128)
//             lgkmcnt(0); barrier  — all waves done reading buf
//             STAGE(t+2 -> same buf)   [back to 16 outstanding]
//             32 MFMA (sub1)
// Last-iter peel: vmcnt(0).
//
// LDS swizzle (both-sides involution, rule #21): rows are 128B (BK=64 f16)
// == exactly 32 banks, so un-swizzled column reads are 16-way conflicts.
// k-chunk (16B) is XORed with (row&7) on BOTH the pre-swizzled global
// source of global_load_lds and the ds_read offset; row&7 is invariant
// under +16/+8-row steps used by fragments/staging so offsets are loop-
// invariant. Post-swizzle: 16 lanes span 8 bank-quads = 2-way = free.
//
// 1-D grid, batch = xcd (assumes hw xcd = blockIdx.x % 8):
//  SWZ=1 (GEMM1): 3x3 tiles, 8 batches, ksplit=2 (atomic).  grid 144.
//  SWZ=2 (GEMM2): 16x3 tiles, 8 batches, no split.          grid 384.
// ---------------------------------------------------------------------------
template <bool ATOMIC, int SWZ>
__global__ __launch_bounds__(512, 2) void k_gemm_bt(
    const f16* __restrict__ A, const f16* __restrict__ B,
    float* __restrict__ C, int klen, int lda, int ldb, int ldc,
    size_t sA, size_t sB, size_t sC) {
  __shared__ __align__(16) f16 As[2][256 * 64];
  __shared__ __align__(16) f16 Bs[2][256 * 64];

  const int lin = blockIdx.x;
  const int xcd = lin & 7;
  const int slot = lin >> 3;
  int bx, by, ks;
  const int b = xcd;               // one batch per XCD
  if (SWZ == 1) {
    ks = slot / 9;                 // 2 K-split phases
    const int item = slot % 9;
    bx = item % 3;
    by = item / 3;
  } else {
    ks = 0;
    by = slot % 3;                 // 3 consecutive tiles share the B chunk
    bx = slot / 3;
  }

  const f16* Ap = A + (size_t)b * sA + (size_t)by * 256 * lda + (size_t)ks * klen;
  const f16* Bp = B + (size_t)b * sB + (size_t)bx * 256 * ldb + (size_t)ks * klen;
  float* Cp = C + (size_t)b * sC + (size_t)by * 256 * ldc + bx * 256;

  const int tid = threadIdx.x;
  const int wave = tid >> 6;
  const int lane = tid & 63;
  const int wr = wave >> 2;   // 0/1  -> M half (128 rows)
  const int wn = wave & 3;    // 0..3 -> N quarter (64 cols)

  // --- staging geometry: wave w stages A rows [32w,32w+32) and B rows ditto,
  // as 4 chunks of (8 rows x 64k) = 1KB each. LDS dest is linear
  // (global_load_lds), global source k-chunk is pre-swizzled by row&7.
  const int srow = lane >> 3;                    // 0..7 (row within chunk)
  const int ssw = ((lane & 7) ^ srow) * 8;       // swizzled source k-offset (f16)
  const f16* gA = Ap + (size_t)(wave * 32 + srow) * lda + ssw;
  const f16* gB = Bp + (size_t)(wave * 32 + srow) * ldb + ssw;
  const int cb = wave * 4 * 512;                 // wave's chunk-0 LDS offset (f16)

  // --- fragment read offsets: lane holds row (lane&15), k-chunk (lane>>4),
  // with the same XOR; row&7 == (lane&15)&7 is invariant under +16-row steps.
  const int mrow = lane & 15;
  const int kk = lane >> 4;                      // 0..3
  const int asw = ((kk ^ (mrow & 7)) * 8);
  const int raofs = (wr * 128 + mrow) * 64 + asw;
  const int rbofs = (wn * 64 + mrow) * 64 + asw;

  f32x4 acc[8][4] = {};

  const int nit = klen >> 6;

#define STAGE(bufi)                                                          \
  do {                                                                       \
    _Pragma("unroll") for (int q = 0; q < 4; ++q) {                          \
      GLDS16(gA + (size_t)q * 8 * lda, &As[bufi][cb + q * 512]);             \
      GLDS16(gB + (size_t)q * 8 * ldb, &Bs[bufi][cb + q * 512]);             \
    }                                                                        \
  } while (0)

  // prologue: tiles 0 and 1
  STAGE(0);
  gA += 64; gB += 64;
  STAGE(1);

  for (int it = 0; it < nit; ++it) {
    const int buf = it & 1;
    if (it + 1 < nit)
      asm volatile("s_waitcnt vmcnt(8)" ::: "memory");
    else
      asm volatile("s_waitcnt vmcnt(0)" ::: "memory");
    __builtin_amdgcn_s_barrier();
    __builtin_amdgcn_sched_barrier(0);

    const f16* la = &As[buf][0];
    const f16* lb = &Bs[buf][0];
    f16x8 af[8], bf[4];
    // ---- k-sub 0: reads + MFMA
#pragma unroll
    for (int i = 0; i < 8; ++i)
      af[i] = *reinterpret_cast<const f16x8*>(la + raofs + i * 1024);
#pragma unroll
    for (int j = 0; j < 4; ++j)
      bf[j] = *reinterpret_cast<const f16x8*>(lb + rbofs + j * 1024);
#pragma unroll
    for (int i = 0; i < 8; ++i)
#pragma unroll
      for (int j = 0; j < 4; ++j)
        acc[i][j] = __builtin_amdgcn_mfma_f32_16x16x32_f16(af[i], bf[j],
                                                           acc[i][j], 0, 0, 0);
    // ---- k-sub 1: reads (k-chunk ^4 under the swizzle == offset ^32)
#pragma unroll
    for (int i = 0; i < 8; ++i)
      af[i] = *reinterpret_cast<const f16x8*>(la + ((raofs + i * 1024) ^ 32));
#pragma unroll
    for (int j = 0; j < 4; ++j)
      bf[j] = *reinterpret_cast<const f16x8*>(lb + ((rbofs + j * 1024) ^ 32));
    asm volatile("s_waitcnt lgkmcnt(0)" ::: "memory");
    __builtin_amdgcn_sched_barrier(0);
    __builtin_amdgcn_s_barrier();   // all waves finished reading buf
    __builtin_amdgcn_sched_barrier(0);
    if (it + 2 < nit) {
      gA += 64; gB += 64;
      STAGE(buf);                   // refill just-read buffer with tile t+2
    }
#pragma unroll
    for (int i = 0; i < 8; ++i)
#pragma unroll
      for (int j = 0; j < 4; ++j)
        acc[i][j] = __builtin_amdgcn_mfma_f32_16x16x32_f16(af[i], bf[j],
                                                           acc[i][j], 0, 0, 0);
  }
#undef STAGE

  // C/D layout (verified m89/m91, dtype-independent): col=lane&15, row=(lane>>4)*4+reg
  const int col = lane & 15;
  const int rq = kk * 4;
#pragma unroll
  for (int i = 0; i < 8; ++i) {
    const int r0 = wr * 128 + i * 16 + rq;
#pragma unroll
    for (int j = 0; j < 4; ++j) {
      const int cidx = wn * 64 + j * 16 + col;
#pragma unroll
      for (int r = 0; r < 4; ++r) {
        const float v = acc[i][j][r];
        if (ATOMIC)
          atomicAdd(&Cp[(size_t)(r0 + r) * ldc + cidx], v);
        else
          Cp[(size_t)(r0 + r) * ldc + cidx] = v;
      }
    }
  }
}

// ---------------------------------------------------------------------------
// Kernel C: row softmax over 768 logits (SCALE applied here), fp32 -> fp16.
// ---------------------------------------------------------------------------
__global__ __launch_bounds__(256) void k_softmax(const float* __restrict__ S,
                                                 f16* __restrict__ P) {
  const int row = blockIdx.x * 4 + (threadIdx.x >> 6);
  const int lane = threadIdx.x & 63;
  const float* s = S + (size_t)row * CC;
  float v[12];
#pragma unroll
  for (int j = 0; j < 3; ++j) {
    const float4 t = *reinterpret_cast<const float4*>(&s[j * 256 + lane * 4]);
    v[j * 4 + 0] = t.x * SCALE_F;
    v[j * 4 + 1] = t.y * SCALE_F;
    v[j * 4 + 2] = t.z * SCALE_F;
    v[j * 4 + 3] = t.w * SCALE_F;
  }
  float m = v[0];
#pragma unroll
  for (int j = 1; j < 12; ++j) m = fmaxf(m, v[j]);
#pragma unroll
  for (int off = 32; off >= 1; off >>= 1) m = fmaxf(m, __shfl_xor(m, off, 64));
  float sum = 0.f;
#pragma unroll
  for (int j = 0; j < 12; ++j) {
    v[j] = __expf(v[j] - m);
    sum += v[j];
  }
#pragma unroll
  for (int off = 32; off >= 1; off >>= 1) sum += __shfl_xor(sum, off, 64);
  const float inv = 1.0f / sum;
  f16* p = P + (size_t)row * CC;
#pragma unroll
  for (int j = 0; j < 3; ++j) {
    f16x4 o = {(f16)(v[j * 4 + 0] * inv), (f16)(v[j * 4 + 1] * inv),
               (f16)(v[j * 4 + 2] * inv), (f16)(v[j * 4 + 3] * inv)};
    *reinterpret_cast<f16x4*>(&p[j * 256 + lane * 4]) = o;
  }
}

// ---------------------------------------------------------------------------
extern "C" void kernel_launch(void* const* d_in, const int* in_sizes, int n_in,
                              void* d_out, int out_size, void* d_ws,
                              size_t ws_size, hipStream_t stream) {
  const float* x1 = (const float*)d_in[0];
  const float* x2 = (const float*)d_in[1];
  float* out = (float*)d_out;

  const size_t elems = (size_t)NB * NN * CC;  // 25165824
  // x1t/x2t live in d_out (2 * f16 arrays == out fp32 bytes exactly);
  // GEMM2 overwrites out only after GEMM1 consumed them.
  f16* x1t = (f16*)d_out;
  f16* x2t = x1t + elems;
  char* ws = (char*)d_ws;
  f16* x2b = (f16*)ws;                                     // 50.3 MB
  float* S = (float*)(ws + elems * 2);                     // 18.9 MB
  f16* P = (f16*)(ws + elems * 2 + (size_t)NB * CC * CC * 4);  // 9.4 MB
  const size_t need =
      elems * 2 + (size_t)NB * CC * CC * 4 + (size_t)NB * CC * CC * 2;
  if (ws_size < need) return;  // cannot run without scratch

  // A) convert + transpose
  k_convert<<<dim3(NN / 64, CC / 64, 2 * NB), 256, 0, stream>>>(x1, x2, x1t,
                                                                x2t, x2b);
  // B) S = x1t . x2t^T  (split-K x2, atomic accumulate; S pre-zeroed)
  hipMemsetAsync(S, 0, (size_t)NB * CC * CC * 4, stream);
  k_gemm_bt<true, 1><<<dim3(9 * NB * 2), 512, 0, stream>>>(
      x1t, x2t, S, NN / 2, NN, NN, CC, (size_t)CC * NN, (size_t)CC * NN,
      (size_t)CC * CC);
  // C) P = softmax(SCALE * S) as fp16
  k_softmax<<<dim3(NB * CC / 4), 256, 0, stream>>>(S, P);
  // D) out = P . x2b^T
  k_gemm_bt<false, 2><<<dim3(16 * 3 * NB), 512, 0, stream>>>(
      P, x2b, out, CC, CC, CC, NN, (size_t)CC * CC, (size_t)NN * CC,
      (size_t)CC * NN);
}